// Round 6
// baseline (418.669 us; speedup 1.0000x reference)
//
#include <hip/hip_runtime.h>
#include <math.h>

#define N_NODES 50000
#define N_EDGES 400000
#define N_GRAPHS 16
#define HEADS 4
#define NEG_SLOPE 0.2f
#define MAX_DEG 64
#define NTILES 1563   // ceil(N_NODES/32)

typedef __attribute__((ext_vector_type(8))) short short8;
typedef __attribute__((ext_vector_type(4))) float floatx4;
typedef _Float16 half_t;
typedef _Float16 half2_t __attribute__((ext_vector_type(2)));
typedef _Float16 half4_t __attribute__((ext_vector_type(4)));

__device__ __forceinline__ unsigned short f2bf(float x) {
    union { float f; unsigned int u; } v; v.f = x;
    unsigned int r = v.u + 0x7fffu + ((v.u >> 16) & 1u);
    return (unsigned short)(r >> 16);
}
__device__ __forceinline__ float bf2f(unsigned short b) {
    union { unsigned int u; float f; } v; v.u = ((unsigned int)b) << 16;
    return v.f;
}
__device__ __forceinline__ half2_t u2h2(unsigned int u) {
    union { unsigned int i; half2_t h; } v; v.i = u;
    return v.h;
}
__device__ __forceinline__ float fast_tanh(float x) {
    float e = __expf(2.f * x);
    return 1.f - 2.f / (e + 1.f);
}
__device__ __forceinline__ half2_t lrelu2(half2_t e) {
    half2_t s = e * (half2_t){(half_t)NEG_SLOPE, (half_t)NEG_SLOPE};
    return __builtin_elementwise_max(e, s);
}
__device__ __forceinline__ float dot2acc(half2_t a, half2_t b, float c) {
#if __has_builtin(__builtin_amdgcn_fdot2)
    return __builtin_amdgcn_fdot2(a, b, c, false);
#else
    return c + (float)a[0] * (float)b[0] + (float)a[1] * (float)b[1];
#endif
}

// ---------------- shared agg-per-node body (R5 flat-chain version) ----------------
// eid: sanitized edge node-id held by this lane; deg: clamped in-degree.
// Outputs o[0..3] valid on lanes with (lane&31)<8, already head-summed.
__device__ __forceinline__ void agg_node(const char* __restrict__ fsb,
                                         const half2_t* at2, const half2_t* fd2,
                                         int eid, int deg, int slot, unsigned boff,
                                         float* o) {
    float l = 0.f;
    half2_t zero2 = {(half_t)0.f, (half_t)0.f};
    half2_t acc2[4] = {zero2, zero2, zero2, zero2};
    int j = 0;
    do {
        int i0 = j + slot, i1 = j + 2 + slot, i2 = j + 4 + slot, i3 = j + 6 + slot;
        bool v0 = i0 < deg, v1 = i1 < deg, v2 = i2 < deg, v3 = i3 < deg;
        int s0 = __shfl(eid, i0 & 63, 64);
        int s1 = __shfl(eid, i1 & 63, 64);
        int s2 = __shfl(eid, i2 & 63, 64);
        int s3 = __shfl(eid, i3 & 63, 64);
        uint4 g0 = *(const uint4*)(fsb + (((unsigned)s0 << 9) + boff));
        uint4 g1 = *(const uint4*)(fsb + (((unsigned)s1 << 9) + boff));
        uint4 g2 = *(const uint4*)(fsb + (((unsigned)s2 << 9) + boff));
        uint4 g3 = *(const uint4*)(fsb + (((unsigned)s3 << 9) + boff));
        half2_t f0[4] = {u2h2(g0.x), u2h2(g0.y), u2h2(g0.z), u2h2(g0.w)};
        half2_t f1[4] = {u2h2(g1.x), u2h2(g1.y), u2h2(g1.z), u2h2(g1.w)};
        half2_t f2[4] = {u2h2(g2.x), u2h2(g2.y), u2h2(g2.z), u2h2(g2.w)};
        half2_t f3[4] = {u2h2(g3.x), u2h2(g3.y), u2h2(g3.z), u2h2(g3.w)};
        float p0 = 0.f, p1 = 0.f, p2 = 0.f, p3 = 0.f;
        #pragma unroll
        for (int k = 0; k < 4; k++) {
            p0 = dot2acc(at2[k], lrelu2(f0[k] + fd2[k]), p0);
            p1 = dot2acc(at2[k], lrelu2(f1[k] + fd2[k]), p1);
            p2 = dot2acc(at2[k], lrelu2(f2[k] + fd2[k]), p2);
            p3 = dot2acc(at2[k], lrelu2(f3[k] + fd2[k]), p3);
        }
        p0 += __shfl_xor(p0, 1, 64); p1 += __shfl_xor(p1, 1, 64);
        p2 += __shfl_xor(p2, 1, 64); p3 += __shfl_xor(p3, 1, 64);
        p0 += __shfl_xor(p0, 2, 64); p1 += __shfl_xor(p1, 2, 64);
        p2 += __shfl_xor(p2, 2, 64); p3 += __shfl_xor(p3, 2, 64);
        p0 += __shfl_xor(p0, 4, 64); p1 += __shfl_xor(p1, 4, 64);
        p2 += __shfl_xor(p2, 4, 64); p3 += __shfl_xor(p3, 4, 64);
        float w0 = v0 ? __expf(fminf(p0, 80.f)) : 0.f;
        float w1 = v1 ? __expf(fminf(p1, 80.f)) : 0.f;
        float w2 = v2 ? __expf(fminf(p2, 80.f)) : 0.f;
        float w3 = v3 ? __expf(fminf(p3, 80.f)) : 0.f;
        l += (w0 + w1) + (w2 + w3);
        half_t hw0 = (half_t)w0, hw1 = (half_t)w1, hw2 = (half_t)w2, hw3 = (half_t)w3;
        half2_t w02 = {hw0, hw0}, w12 = {hw1, hw1}, w22 = {hw2, hw2}, w32 = {hw3, hw3};
        #pragma unroll
        for (int k = 0; k < 4; k++) {
            acc2[k] += w02 * f0[k];
            acc2[k] += w12 * f1[k];
            acc2[k] += w22 * f2[k];
            acc2[k] += w32 * f3[k];
        }
        j += 8;
    } while (j < deg);
    l += __shfl_xor(l, 32, 64);
    #pragma unroll
    for (int k = 0; k < 4; k++) {
        float t = __builtin_bit_cast(float, acc2[k]);
        t = __shfl_xor(t, 32, 64);
        acc2[k] += __builtin_bit_cast(half2_t, t);
    }
    float inv = (l > 0.f) ? 1.f / l : 0.f;
    half2_t a0 = slot ? acc2[2] : acc2[0];
    half2_t a1 = slot ? acc2[3] : acc2[1];
    o[0] = fast_tanh((float)a0[0] * inv);
    o[1] = fast_tanh((float)a0[1] * inv);
    o[2] = fast_tanh((float)a1[0] * inv);
    o[3] = fast_tanh((float)a1[1] * inv);
    o[0] += __shfl_xor(o[0], 8, 64);  o[0] += __shfl_xor(o[0], 16, 64);
    o[1] += __shfl_xor(o[1], 8, 64);  o[1] += __shfl_xor(o[1], 16, 64);
    o[2] += __shfl_xor(o[2], 8, 64);  o[2] += __shfl_xor(o[2], 16, 64);
    o[3] += __shfl_xor(o[3], 8, 64);  o[3] += __shfl_xor(o[3], 16, 64);
}

// ---------------- fused h0 + weight pack + zero cursor/hg ----------------
__global__ __launch_bounds__(256) void k_h0_pack(const float* __restrict__ feat,
                                                 const float* __restrict__ W_in,
                                                 const float* __restrict__ b_in,
                                                 unsigned short* __restrict__ h0,
                                                 const float* __restrict__ Wsrc,
                                                 const float* __restrict__ Wdst,
                                                 unsigned short* __restrict__ Wpack,
                                                 int* __restrict__ cursor,
                                                 float* __restrict__ hg) {
    int bid = blockIdx.x;
    if (bid < 12500) {
        int idx = bid * 256 + threadIdx.x;
        int node = idx >> 6, d = idx & 63;
        float acc = b_in[d];
        #pragma unroll
        for (int k = 0; k < 16; k++) acc += feat[node * 16 + k] * W_in[k * 64 + d];
        h0[idx] = f2bf(acc);
    } else if (bid < 12756) {
        int pb = bid - 12500;
        int mat = pb >> 7;
        int idx = (pb & 127) * 256 + threadIdx.x;
        const float* W = mat ? Wdst : Wsrc;
        int j = idx & 7;
        int lane = (idx >> 3) & 63;
        int q = (idx >> 9) & 3;
        int t = (idx >> 11) & 15;
        int col = t * 16 + (lane & 15);
        int k = q * 32 + (lane >> 4) * 8 + j;
        Wpack[mat * 32768 + idx] = f2bf(W[k * 256 + col]);
    } else if (bid < 12952) {
        int idx = (bid - 12756) * 256 + threadIdx.x;
        if (idx < N_NODES) cursor[idx] = 0;
    } else {
        for (int i = threadIdx.x; i < N_GRAPHS * 64; i += 256) hg[i] = 0.f;
    }
}

// ---------------- one-pass padded-CSR bucket fill ----------------
__global__ __launch_bounds__(256) void k_fill(const int* __restrict__ src, const int* __restrict__ dst,
                                              int* __restrict__ cursor, int* __restrict__ csr_pad, int e) {
    int i = blockIdx.x * 256 + threadIdx.x;
    if (i >= e) return;
    int d = dst[i];
    int slot = atomicAdd(&cursor[d], 1);
    if (slot < MAX_DEG) csr_pad[d * MAX_DEG + slot] = src[i];
}

// ---------------- first-layer gemm (R5 exact): fs/fd = [h0|h0] @ W + b ----------------
__global__ __launch_bounds__(256) void k_gemm(const unsigned short* __restrict__ h,
                                              const unsigned short* __restrict__ h0,
                                              const unsigned short* __restrict__ Wpack,
                                              const float* __restrict__ bsrc,
                                              const float* __restrict__ bdst,
                                              half_t* __restrict__ fs,
                                              half_t* __restrict__ fd, int n) {
    __shared__ half_t tile[32][264];
    int mat = blockIdx.y;
    const unsigned short* Wp = Wpack + mat * 32768;
    const float* bias = mat ? bdst : bsrc;
    half_t* out = mat ? fd : fs;
    int wave = threadIdx.x >> 6, lane = threadIdx.x & 63;
    int quad = lane >> 4, m16 = lane & 15;
    int fhalf = wave & 1;
    int ngrp = wave >> 1;
    int node0 = blockIdx.x * 32 + ngrp * 16;

    floatx4 acc[8];
    #pragma unroll
    for (int t = 0; t < 8; t++) acc[t] = (floatx4){0.f, 0.f, 0.f, 0.f};

    int r = node0 + m16;
    if (r > n - 1) r = n - 1;

    #pragma unroll
    for (int q = 0; q < 4; q++) {
        int kk = q * 32 + quad * 8;
        const unsigned short* base = (kk < 64) ? (h + (size_t)r * 64 + kk)
                                               : (h0 + (size_t)r * 64 + (kk - 64));
        short8 x = *(const short8*)base;
        #pragma unroll
        for (int t = 0; t < 8; t++) {
            int tt = fhalf * 8 + t;
            short8 w = *(const short8*)(Wp + ((size_t)(tt * 4 + q) * 64 + lane) * 8);
            acc[t] = __builtin_amdgcn_mfma_f32_16x16x32_bf16(w, x, acc[t], 0, 0, 0);
        }
    }
    int lrow = ngrp * 16 + m16;
    #pragma unroll
    for (int t = 0; t < 8; t++) {
        int fbase = (fhalf * 8 + t) * 16 + quad * 4;
        float4 bb = *(const float4*)(bias + fbase);
        half4_t ov = { (half_t)(acc[t][0] + bb.x), (half_t)(acc[t][1] + bb.y),
                       (half_t)(acc[t][2] + bb.z), (half_t)(acc[t][3] + bb.w) };
        *(half4_t*)&tile[lrow][fbase] = ov;
    }
    __syncthreads();
    int base = blockIdx.x * 32;
    for (int i = threadIdx.x; i < 1024; i += 256) {
        int row = i >> 5, seg = i & 31;
        int node = base + row;
        if (node < n) {
            uint4 v = *(const uint4*)&tile[row][seg * 8];
            *(uint4*)(out + (size_t)node * 256 + seg * 8) = v;
        }
    }
}

// ---------------- fused layer: agg(layer k) -> h in LDS -> gemm(layer k+1) ----------------
// Block owns nodes [32b, 32b+32). Wave aggs 8 nodes (prefetch-next pipelined),
// h handed to gemm through padded LDS tile (no global h traffic).
// Reads fs_in/fd_in (previous dispatch), writes fs_out/fd_out (double buffer).
__global__ __launch_bounds__(256) void k_layer(
    const half_t* __restrict__ fs_in, const half_t* __restrict__ fd_in,
    const int* __restrict__ cnt, const int* __restrict__ csr_pad,
    const float* __restrict__ attn,
    const unsigned short* __restrict__ h0,
    const unsigned short* __restrict__ Wpack,
    const float* __restrict__ bsrc, const float* __restrict__ bdst,
    half_t* __restrict__ fs_out, half_t* __restrict__ fd_out, int n)
{
    __shared__ half_t tile[32][264];          // gemm staging
    __shared__ unsigned short h_tile[32][72]; // bf16 h, row pad +8 -> 2-way banks (free)
    const int tid = threadIdx.x;
    const int wave = tid >> 6, lane = tid & 63;
    const int tile_base = blockIdx.x * 32;

    // ---- agg phase ----
    {
        const int slot = lane >> 5;
        const int foff = ((lane >> 3) & 3) * 64 + (lane & 7) * 8;
        const unsigned boff = (unsigned)foff * 2;
        const char* fsb = (const char*)fs_in;
        half2_t at2[4];
        {
            float4 a0 = *(const float4*)(attn + foff);
            float4 a1 = *(const float4*)(attn + foff + 4);
            at2[0] = (half2_t){(half_t)a0.x, (half_t)a0.y};
            at2[1] = (half2_t){(half_t)a0.z, (half_t)a0.w};
            at2[2] = (half2_t){(half_t)a1.x, (half_t)a1.y};
            at2[3] = (half2_t){(half_t)a1.z, (half_t)a1.w};
        }
        int gbase = tile_base + wave * 8;
        int pn = gbase; if (pn > n - 1) pn = n - 1;
        int eraw = csr_pad[pn * MAX_DEG + lane];
        int degn = cnt[pn];
        uint4 ufd = *(const uint4*)(fd_in + (size_t)pn * 256 + foff);
        for (int nd = 0; nd < 8; nd++) {
            int ceraw = eraw, cdeg = degn;
            uint4 cufd = ufd;
            if (nd < 7) {
                int nx = gbase + nd + 1; if (nx > n - 1) nx = n - 1;
                eraw = csr_pad[nx * MAX_DEG + lane];
                degn = cnt[nx];
                ufd = *(const uint4*)(fd_in + (size_t)nx * 256 + foff);
            }
            half2_t fd2[4] = {u2h2(cufd.x), u2h2(cufd.y), u2h2(cufd.z), u2h2(cufd.w)};
            if (cdeg > MAX_DEG) cdeg = MAX_DEG;
            int eid = (lane < cdeg) ? ceraw : 0;
            float o[4];
            agg_node(fsb, at2, fd2, eid, cdeg, slot, boff, o);
            if ((lane & 31) < 8) {
                ushort4 ov = {f2bf(o[0]), f2bf(o[1]), f2bf(o[2]), f2bf(o[3])};
                *(ushort4*)&h_tile[wave * 8 + nd][(lane & 7) * 8 + slot * 4] = ov;
            }
        }
    }
    __syncthreads();

    // ---- gemm phase (2-mat loop, x: h from LDS, h0 from global) ----
    const int quad = lane >> 4, m16 = lane & 15;
    const int fhalf = wave & 1, ngrp = wave >> 1;
    int lrow = ngrp * 16 + m16;
    int r = tile_base + lrow;
    if (r > n - 1) r = n - 1;

    short8 x[4];
    x[0] = *(const short8*)&h_tile[lrow][quad * 8];
    x[1] = *(const short8*)&h_tile[lrow][32 + quad * 8];
    x[2] = *(const short8*)(h0 + (size_t)r * 64 + quad * 8);
    x[3] = *(const short8*)(h0 + (size_t)r * 64 + 32 + quad * 8);

    #pragma unroll
    for (int mat = 0; mat < 2; mat++) {
        const unsigned short* Wp = Wpack + mat * 32768;
        const float* bias = mat ? bdst : bsrc;
        half_t* outp = mat ? fd_out : fs_out;

        floatx4 acc[8];
        #pragma unroll
        for (int t = 0; t < 8; t++) acc[t] = (floatx4){0.f, 0.f, 0.f, 0.f};

        #pragma unroll
        for (int q = 0; q < 4; q++) {
            #pragma unroll
            for (int t = 0; t < 8; t++) {
                int tt = fhalf * 8 + t;
                short8 wv = *(const short8*)(Wp + ((size_t)(tt * 4 + q) * 64 + lane) * 8);
                acc[t] = __builtin_amdgcn_mfma_f32_16x16x32_bf16(wv, x[q], acc[t], 0, 0, 0);
            }
        }
        #pragma unroll
        for (int t = 0; t < 8; t++) {
            int fbase = (fhalf * 8 + t) * 16 + quad * 4;
            float4 bb = *(const float4*)(bias + fbase);
            half4_t ov = { (half_t)(acc[t][0] + bb.x), (half_t)(acc[t][1] + bb.y),
                           (half_t)(acc[t][2] + bb.z), (half_t)(acc[t][3] + bb.w) };
            *(half4_t*)&tile[lrow][fbase] = ov;
        }
        __syncthreads();
        for (int i = tid; i < 1024; i += 256) {
            int row = i >> 5, seg = i & 31;
            int node = tile_base + row;
            if (node < n) {
                uint4 v = *(const uint4*)&tile[row][seg * 8];
                *(uint4*)(outp + (size_t)node * 256 + seg * 8) = v;
            }
        }
        if (mat == 0) __syncthreads();
    }
}

// ---------------- final layer: agg -> LDS -> graph readout (segment atomics) ----------------
__global__ __launch_bounds__(256) void k_aggro(
    const half_t* __restrict__ fs_in, const half_t* __restrict__ fd_in,
    const int* __restrict__ cnt, const int* __restrict__ csr_pad,
    const float* __restrict__ attn,
    const float* __restrict__ is_root, const int* __restrict__ gid,
    float* __restrict__ hg, int n)
{
    __shared__ unsigned short h_tile[32][72];
    const int tid = threadIdx.x;
    const int wave = tid >> 6, lane = tid & 63;
    const int tile_base = blockIdx.x * 32;

    {
        const int slot = lane >> 5;
        const int foff = ((lane >> 3) & 3) * 64 + (lane & 7) * 8;
        const unsigned boff = (unsigned)foff * 2;
        const char* fsb = (const char*)fs_in;
        half2_t at2[4];
        {
            float4 a0 = *(const float4*)(attn + foff);
            float4 a1 = *(const float4*)(attn + foff + 4);
            at2[0] = (half2_t){(half_t)a0.x, (half_t)a0.y};
            at2[1] = (half2_t){(half_t)a0.z, (half_t)a0.w};
            at2[2] = (half2_t){(half_t)a1.x, (half_t)a1.y};
            at2[3] = (half2_t){(half_t)a1.z, (half_t)a1.w};
        }
        int gbase = tile_base + wave * 8;
        int pn = gbase; if (pn > n - 1) pn = n - 1;
        int eraw = csr_pad[pn * MAX_DEG + lane];
        int degn = cnt[pn];
        uint4 ufd = *(const uint4*)(fd_in + (size_t)pn * 256 + foff);
        for (int nd = 0; nd < 8; nd++) {
            int ceraw = eraw, cdeg = degn;
            uint4 cufd = ufd;
            if (nd < 7) {
                int nx = gbase + nd + 1; if (nx > n - 1) nx = n - 1;
                eraw = csr_pad[nx * MAX_DEG + lane];
                degn = cnt[nx];
                ufd = *(const uint4*)(fd_in + (size_t)nx * 256 + foff);
            }
            half2_t fd2[4] = {u2h2(cufd.x), u2h2(cufd.y), u2h2(cufd.z), u2h2(cufd.w)};
            if (cdeg > MAX_DEG) cdeg = MAX_DEG;
            int eid = (lane < cdeg) ? ceraw : 0;
            float o[4];
            agg_node(fsb, at2, fd2, eid, cdeg, slot, boff, o);
            if ((lane & 31) < 8) {
                ushort4 ov = {f2bf(o[0]), f2bf(o[1]), f2bf(o[2]), f2bf(o[3])};
                *(ushort4*)&h_tile[wave * 8 + nd][(lane & 7) * 8 + slot * 4] = ov;
            }
        }
    }
    __syncthreads();

    // readout: wave sums its 8 nodes (lane = dim), segment atomics on gid changes
    int gbase = tile_base + wave * 8;
    if (gbase < n) {
        int stop = gbase + 8; if (stop > n) stop = n;
        float racc = 0.f;
        int cur = gid[gbase];
        for (int i = gbase; i < stop; i++) {
            int g = gid[i];
            if (g != cur) {
                atomicAdd(&hg[cur * 64 + lane], racc);
                racc = 0.f;
                cur = g;
            }
            racc += bf2f(h_tile[i - tile_base][lane]) * is_root[i];
        }
        atomicAdd(&hg[cur * 64 + lane], racc);
    }
}

__global__ __launch_bounds__(512) void k_out(const float* __restrict__ hg, const float* __restrict__ W_out,
                                             const float* __restrict__ b_out, float* __restrict__ out) {
    int t = threadIdx.x;
    if (t >= N_GRAPHS * 32) return;
    int b = t >> 5, c = t & 31;
    float a = b_out[c];
    #pragma unroll
    for (int d = 0; d < 64; d++) a += hg[b * 64 + d] * W_out[d * 32 + c];
    out[t] = a;
}

extern "C" void kernel_launch(void* const* d_in, const int* in_sizes, int n_in,
                              void* d_out, int out_size, void* d_ws, size_t ws_size,
                              hipStream_t stream) {
    const float* feat    = (const float*)d_in[0];
    const float* is_root = (const float*)d_in[1];
    const int*   src     = (const int*)d_in[2];
    const int*   dst     = (const int*)d_in[3];
    const int*   gid     = (const int*)d_in[4];
    const float* W_in    = (const float*)d_in[5];
    const float* b_in    = (const float*)d_in[6];
    const float* W_src   = (const float*)d_in[7];
    const float* b_src   = (const float*)d_in[8];
    const float* W_dst   = (const float*)d_in[9];
    const float* b_dst   = (const float*)d_in[10];
    const float* attn    = (const float*)d_in[11];
    const float* W_out   = (const float*)d_in[12];
    const float* b_out   = (const float*)d_in[13];
    float* out = (float*)d_out;

    char* ws = (char*)d_ws;
    size_t off = 0;
    auto take = [&](size_t bytes) -> char* {
        char* p = ws + off;
        off = (off + bytes + 255) & ~(size_t)255;
        return p;
    };
    half_t* fsA           = (half_t*)take((size_t)N_NODES * 256 * 2);
    half_t* fdA           = (half_t*)take((size_t)N_NODES * 256 * 2);
    half_t* fsB           = (half_t*)take((size_t)N_NODES * 256 * 2);
    half_t* fdB           = (half_t*)take((size_t)N_NODES * 256 * 2);
    unsigned short* h0    = (unsigned short*)take((size_t)N_NODES * 64 * 2);
    unsigned short* Wpack = (unsigned short*)take((size_t)2 * 32768 * 2);
    float* hg             = (float*)take((size_t)N_GRAPHS * 64 * 4);
    int*   cursor         = (int*)take((size_t)N_NODES * 4);
    int*   csr_pad        = (int*)take((size_t)N_NODES * MAX_DEG * 4);

    const int n = N_NODES, e = N_EDGES;
    dim3 b256(256);

    // h0 + weight pack + zero cursor/hg
    k_h0_pack<<<dim3(12953), b256, 0, stream>>>(feat, W_in, b_in, h0, W_src, W_dst, Wpack, cursor, hg);
    // padded-CSR build
    k_fill<<<dim3((e + 255) / 256), b256, 0, stream>>>(src, dst, cursor, csr_pad, e);

    // layer 0 gemm
    k_gemm<<<dim3(NTILES, 2), b256, 0, stream>>>(h0, h0, Wpack, b_src, b_dst, fsA, fdA, n);
    // fused: agg0+gemm1, agg1+gemm2, agg2+gemm3
    k_layer<<<dim3(NTILES), b256, 0, stream>>>(fsA, fdA, cursor, csr_pad, attn, h0, Wpack,
                                               b_src, b_dst, fsB, fdB, n);
    k_layer<<<dim3(NTILES), b256, 0, stream>>>(fsB, fdB, cursor, csr_pad, attn, h0, Wpack,
                                               b_src, b_dst, fsA, fdA, n);
    k_layer<<<dim3(NTILES), b256, 0, stream>>>(fsA, fdA, cursor, csr_pad, attn, h0, Wpack,
                                               b_src, b_dst, fsB, fdB, n);
    // final: agg3 + readout
    k_aggro<<<dim3(NTILES), b256, 0, stream>>>(fsB, fdB, cursor, csr_pad, attn, is_root, gid, hg, n);

    k_out<<<dim3(1), dim3(512), 0, stream>>>(hg, W_out, b_out, out);
}